// Round 5
// baseline (500.267 us; speedup 1.0000x reference)
//
#include <hip/hip_runtime.h>
#include <math.h>

#define HIDDEN 256
#define NUM_CLASSES 53
#define CHUNK 64    // rows per k1 block (N = 4096 * 64 exactly)
#define NSLOT 10    // LDS bag slots per block

// ws layout: repre_un[n_bags*512] f32 | s[2*n_bags] f32 | seg[n_rows] i32

// ---------------- K0: zero accumulators + seg fill (block per bag) ----------
__global__ __launch_bounds__(256) void k0_init(
    const int* __restrict__ scope, int* __restrict__ seg,
    float* __restrict__ repre, float* __restrict__ s)
{
    const int b = blockIdx.x;
    const int t = threadIdx.x;
    repre[(size_t)b * 512 + t]       = 0.f;
    repre[(size_t)b * 512 + 256 + t] = 0.f;
    if (t < 2) s[2 * b + t] = 0.f;
    const int st = scope[b], en = scope[b + 1];
    for (int i = st + t; i < en; i += 256) seg[i] = b;
}

// ---------------- K1: single register-resident balanced pass ----------------
__global__ __launch_bounds__(256, 4) void k1_main(
    const float* __restrict__ x,
    const float* __restrict__ rel_emb0,
    const float* __restrict__ rel_emb1,
    const int* __restrict__ relation_levels,
    const int* __restrict__ label_index,
    const int* __restrict__ seg,
    float* __restrict__ repre,
    float* __restrict__ s)
{
    const int c0   = blockIdx.x * CHUNK;
    const int tid  = threadIdx.x;
    const int lane = tid & 63;
    const int wave = tid >> 6;
    const int half = lane >> 5;
    const int j    = lane & 31;
    const int colb = j * 8;
    const int stream = wave * 2 + half;     // 0..7
    const int r0 = c0 + 8 * stream;         // this stream's 8 contiguous rows

    __shared__ int   s_seg[CHUNK];
    __shared__ float s_acc[NSLOT][2][HIDDEN];   // 20 KB
    __shared__ float s_sum[NSLOT][2];
    __shared__ int   s_used[NSLOT];

    for (int t = tid; t < NSLOT * 2 * HIDDEN; t += 256)
        (&s_acc[0][0][0])[t] = 0.f;
    if (tid < NSLOT) { s_used[tid] = 0; s_sum[tid][0] = 0.f; s_sum[tid][1] = 0.f; }
    if (tid < CHUNK) s_seg[tid] = seg[c0 + tid];
    __syncthreads();
    const int seg0 = s_seg[0];

    // register accumulators for the current bag segment
    float a0[8], a1[8];
    #pragma unroll
    for (int k = 0; k < 8; ++k) { a0[k] = 0.f; a1[k] = 0.f; }
    float se0 = 0.f, se1 = 0.f;
    int cur = s_seg[8 * stream];

    auto flush_seg = [&](int bag) {
        const int sl = bag - seg0;
        if (sl < NSLOT) {
            #pragma unroll
            for (int k = 0; k < 8; ++k) {
                atomicAdd(&s_acc[sl][0][colb + k], a0[k]);
                atomicAdd(&s_acc[sl][1][colb + k], a1[k]);
            }
            if (j == 0) {
                atomicAdd(&s_sum[sl][0], se0);
                atomicAdd(&s_sum[sl][1], se1);
                s_used[sl] = 1;   // benign race, same value
            }
        } else {   // pathological many-bag block: direct global flush
            const size_t base = (size_t)bag * 512;
            #pragma unroll
            for (int k = 0; k < 8; ++k) {
                atomicAdd(&repre[base + colb + k],       a0[k]);
                atomicAdd(&repre[base + 256 + colb + k], a1[k]);
            }
            if (j == 0) {
                atomicAdd(&s[2 * bag],     se0);
                atomicAdd(&s[2 * bag + 1], se1);
            }
        }
        #pragma unroll
        for (int k = 0; k < 8; ++k) { a0[k] = 0.f; a1[k] = 0.f; }
        se0 = 0.f; se1 = 0.f;
    };

    #pragma unroll
    for (int r = 0; r < 8; ++r) {
        const int row = r0 + r;
        const float* xp = x + (size_t)row * HIDDEN + colb;
        const float4 xa = *reinterpret_cast<const float4*>(xp);
        const float4 xb = *reinterpret_cast<const float4*>(xp + 4);
        const int lbl = label_index[row];   // uniform within half -> broadcast
        const int2 rl = *reinterpret_cast<const int2*>(relation_levels + 2 * lbl);
        const float* p0 = rel_emb0 + (size_t)rl.x * HIDDEN + colb;
        const float* p1 = rel_emb1 + (size_t)rl.y * HIDDEN + colb;
        const float4 r0a = *reinterpret_cast<const float4*>(p0);
        const float4 r0b = *reinterpret_cast<const float4*>(p0 + 4);
        const float4 r1a = *reinterpret_cast<const float4*>(p1);
        const float4 r1b = *reinterpret_cast<const float4*>(p1 + 4);

        float lg0 = xa.x*r0a.x + xa.y*r0a.y + xa.z*r0a.z + xa.w*r0a.w
                  + xb.x*r0b.x + xb.y*r0b.y + xb.z*r0b.z + xb.w*r0b.w;
        float lg1 = xa.x*r1a.x + xa.y*r1a.y + xa.z*r1a.z + xa.w*r1a.w
                  + xb.x*r1b.x + xb.y*r1b.y + xb.z*r1b.z + xb.w*r1b.w;

        #pragma unroll
        for (int off = 16; off > 0; off >>= 1) {   // 32-lane allreduce in-half
            lg0 += __shfl_xor(lg0, off, 64);
            lg1 += __shfl_xor(lg1, off, 64);
        }
        const float e0 = __expf(lg0);
        const float e1 = __expf(lg1);

        const int bg = s_seg[8 * stream + r];
        if (bg != cur) { flush_seg(cur); cur = bg; }

        a0[0] += e0 * xa.x;  a0[1] += e0 * xa.y;
        a0[2] += e0 * xa.z;  a0[3] += e0 * xa.w;
        a0[4] += e0 * xb.x;  a0[5] += e0 * xb.y;
        a0[6] += e0 * xb.z;  a0[7] += e0 * xb.w;
        a1[0] += e1 * xa.x;  a1[1] += e1 * xa.y;
        a1[2] += e1 * xa.z;  a1[3] += e1 * xa.w;
        a1[4] += e1 * xb.x;  a1[5] += e1 * xb.y;
        a1[6] += e1 * xb.z;  a1[7] += e1 * xb.w;
        se0 += e0;
        se1 += e1;
    }
    flush_seg(cur);
    __syncthreads();

    // ---- block-level flush of used LDS slots (one atomic pass per bag) ----
    for (int sl = 0; sl < NSLOT; ++sl) {
        if (s_used[sl]) {
            const size_t base = (size_t)(seg0 + sl) * 512;
            atomicAdd(&repre[base + tid],       s_acc[sl][0][tid]);
            atomicAdd(&repre[base + 256 + tid], s_acc[sl][1][tid]);
            if (tid == 0) atomicAdd(&s[2 * (seg0 + sl)],     s_sum[sl][0]);
            if (tid == 1) atomicAdd(&s[2 * (seg0 + sl) + 1], s_sum[sl][1]);
        }
    }
}

// ---------------- K2: normalize + head (wave per bag) -----------------------
__global__ __launch_bounds__(256) void k2_head(
    const float* __restrict__ repre,
    const float* __restrict__ s,
    const float* __restrict__ disc,
    const float* __restrict__ bias,
    float* __restrict__ out)
{
    const int tid  = threadIdx.x;
    const int lane = tid & 63;
    const int wave = tid >> 6;
    const int bag  = blockIdx.x * 4 + wave;

    __shared__ float s_rep[4][2 * HIDDEN];   // 8 KB

    const float s0 = s[2 * bag], s1 = s[2 * bag + 1];
    const float inv0 = (s0 > 0.f) ? 1.f / s0 : 0.f;
    const float inv1 = (s1 > 0.f) ? 1.f / s1 : 0.f;
    const float inv  = (lane < 32) ? inv0 : inv1;   // lane owns cols [8L,8L+8)

    const float4* rp = reinterpret_cast<const float4*>(repre + (size_t)bag * 512 + lane * 8);
    float4 v0 = rp[0], v1 = rp[1];
    v0.x *= inv; v0.y *= inv; v0.z *= inv; v0.w *= inv;
    v1.x *= inv; v1.y *= inv; v1.z *= inv; v1.w *= inv;
    float4* dst = reinterpret_cast<float4*>(&s_rep[wave][lane * 8]);
    dst[0] = v0; dst[1] = v1;
    // same-wave LDS write->read: compiler inserts lgkmcnt wait

    if (lane < NUM_CLASSES) {
        const float4* dr = reinterpret_cast<const float4*>(disc + (size_t)lane * 512);
        const float4* rr = reinterpret_cast<const float4*>(s_rep[wave]);
        float p = 0.f;
        #pragma unroll 8
        for (int k = 0; k < 128; ++k) {
            const float4 d = dr[k];
            const float4 r = rr[k];     // same addr all lanes -> broadcast
            p += d.x * r.x + d.y * r.y + d.z * r.z + d.w * r.w;
        }
        out[bag * NUM_CLASSES + lane] = p + bias[lane];
    }
}

extern "C" void kernel_launch(void* const* d_in, const int* in_sizes, int n_in,
                              void* d_out, int out_size, void* d_ws, size_t ws_size,
                              hipStream_t stream) {
    const float* x               = (const float*)d_in[0];
    const float* rel_emb0        = (const float*)d_in[1];
    const float* rel_emb1        = (const float*)d_in[2];
    const float* disc            = (const float*)d_in[3];
    const float* bias            = (const float*)d_in[4];
    const int*   relation_levels = (const int*)d_in[5];
    const int*   label_index     = (const int*)d_in[6];
    const int*   scope           = (const int*)d_in[7];
    float*       out             = (float*)d_out;

    const int n_bags = in_sizes[7] - 1;      // 4096
    const int n_rows = in_sizes[6];          // 262144

    float* repre = (float*)d_ws;                         // n_bags*512
    float* s_ws  = repre + (size_t)n_bags * 512;         // 2*n_bags
    int*   seg   = (int*)(s_ws + 2 * n_bags);            // n_rows

    k0_init<<<n_bags, 256, 0, stream>>>(scope, seg, repre, s_ws);
    k1_main<<<n_rows / CHUNK, 256, 0, stream>>>(
        x, rel_emb0, rel_emb1, relation_levels, label_index, seg, repre, s_ws);
    k2_head<<<n_bags / 4, 256, 0, stream>>>(repre, s_ws, disc, bias, out);
}